// Round 3
// baseline (469.470 us; speedup 1.0000x reference)
//
#include <hip/hip_runtime.h>
#include <hip/hip_fp16.h>

// Shapes (fixed by the reference setup_inputs)
#define NB 2
#define NH 16
#define NS 2048
#define ND 64

typedef __attribute__((ext_vector_type(8))) _Float16 half8;
typedef __attribute__((ext_vector_type(4))) _Float16 half4;
typedef __attribute__((ext_vector_type(4))) float float4v;

static constexpr int NE  = NB * NH * NS * ND;    // 4,194,304 elems per tensor
static constexpr int TPB = 512;                  // 8 waves
static constexpr int CHW = 512;                  // pass-2 chunk width (cols)
static constexpr int NCH = NS / CHW;             // 4 chunks
static constexpr int EP  = CHW + 8;              // ebuf pitch in halfs (row 16B-aligned)

// LDS layout (bytes): ebuf fp16 | maskb u32 | sums f32 | invs f32 | outb f32
static constexpr int LDS_E     = 16 * EP * 2;        // 16,640
static constexpr int LDS_MASK  = 16 * 64 * 4;        // 4,096
static constexpr int LDS_SUM   = 16 * 4;
static constexpr int LDS_INV   = 16 * 4;
static constexpr int LDS_OUTB  = 2 * 16 * 64 * 4;    // 8,192
static constexpr int LDS_BYTES = LDS_E + LDS_MASK + LDS_SUM + LDS_INV + LDS_OUTB; // 29,056

// ---------------------------------------------------------------------------
// Kernel 1: RoPE(q), RoPE(k) -> fp16.
// ---------------------------------------------------------------------------
__global__ void rope_fp16_kernel(const float* __restrict__ q,
                                 const float* __restrict__ k,
                                 _Float16* __restrict__ qr,
                                 _Float16* __restrict__ kr) {
    int idx = blockIdx.x * blockDim.x + threadIdx.x;
    if (idx >= NE / 2) return;
    int i   = idx & 31;        // freq index
    int row = idx >> 5;        // (b*NH + h)*NS + s
    int s   = row & (NS - 1);

    float inv_freq = expf((float)i * -0.2878231366242710f);  // 10000^(-i/32)
    float ang = (float)s * inv_freq;
    float sn, cs;
    sincosf(ang, &sn, &cs);

    size_t base = (size_t)row * ND + 2 * i;
    float q0 = q[base], q1 = q[base + 1];
    float k0 = k[base], k1 = k[base + 1];
    qr[base]     = (_Float16)(q0 * cs - q1 * sn);
    qr[base + 1] = (_Float16)(q1 * cs + q0 * sn);
    kr[base]     = (_Float16)(k0 * cs - k1 * sn);
    kr[base + 1] = (_Float16)(k1 * cs + k0 * sn);
}

// ---------------------------------------------------------------------------
// Kernel 2: V [b,h,s,d] fp32 -> Vt [b,h,d,s] fp16.
// ---------------------------------------------------------------------------
__global__ void vtrans_fp16_kernel(const float* __restrict__ v,
                                   _Float16* __restrict__ vt) {
    int idx = blockIdx.x * blockDim.x + threadIdx.x;
    if (idx >= NE) return;
    int s  = idx & (NS - 1);
    int d  = (idx >> 11) & (ND - 1);
    int bh = idx >> 17;
    vt[idx] = (_Float16)v[((size_t)bh * NS + s) * ND + d];
}

// ---------------------------------------------------------------------------
// Kernel 3: bit-pack mask int32 [B,1,S,S] -> uint32 [B][S][S/32] via ballot.
// ---------------------------------------------------------------------------
__global__ void maskpack_kernel(const int* __restrict__ mask,
                                unsigned int* __restrict__ mp) {
    size_t idx = (size_t)blockIdx.x * 256 + threadIdx.x;   // over NB*NS*NS
    unsigned long long bal = __ballot(mask[idx] != 0);
    int l = threadIdx.x & 63;
    if (l == 0)       mp[idx >> 5] = (unsigned int)bal;
    else if (l == 32) mp[idx >> 5] = (unsigned int)(bal >> 32);
}

// ---------------------------------------------------------------------------
// Kernel 4: fused attention, one 16-row q-tile per WG, 8 waves, two passes.
//   pass 1: QK^T -> masked exp -> REGISTER row sums (no big LDS) -> invs
//   pass 2: per 512-col chunk: QK^T recompute -> e fp16 in small ebuf ->
//           {score write (normalized, coalesced) + PV MFMA} -> next chunk
// Spreads the 537 MB score-write stream across the whole kernel; 29 KB LDS
// and <=64 VGPRs give 4 WG/CU (32 waves, full occupancy).
// MFMA fragments (guide m89/m91): A lane: row=l&15, k=(l>>4)*8+[0..7];
// B same on B^T rows; C/D: col=l&15, row=(l>>4)*4+reg.
// ---------------------------------------------------------------------------
__global__ __launch_bounds__(TPB, 8)
void attn_fused_kernel(const _Float16* __restrict__ qr,
                       const _Float16* __restrict__ kr,
                       const _Float16* __restrict__ vt,
                       const unsigned int* __restrict__ mp,
                       float* __restrict__ out,
                       float* __restrict__ score) {
    extern __shared__ char lds_raw[];
    _Float16*     ebuf  = (_Float16*)lds_raw;                        // [16][EP]
    unsigned int* maskb = (unsigned int*)(lds_raw + LDS_E);          // [16][64]
    float*        sums  = (float*)(lds_raw + LDS_E + LDS_MASK);      // [16]
    float*        invs  = sums + 16;                                 // [16]
    float*        outb  = invs + 16;                                 // [2][16*64]

    // XCD-aware bijective swizzle: 4096 WGs, 8 XCDs -> contiguous 512 per XCD
    int wgid = (blockIdx.x & 7) * 512 + (blockIdx.x >> 3);
    int qt = wgid & 127;
    int bh = wgid >> 7;
    int b  = bh >> 4;
    int q0 = qt * 16;

    int tid = threadIdx.x;
    int w   = tid >> 6;                   // wave 0..7
    int l   = tid & 63;
    int lm  = l & 15;
    int lp  = l >> 4;

    if (tid < 16) sums[tid] = 0.0f;
    {   // stage packed mask rows q0..q0+15 (4KB, coalesced)
        const unsigned int* mrow = mp + ((size_t)b * NS + q0) * 64;
        for (int i = tid; i < 16 * 64; i += TPB) maskb[i] = mrow[i];
    }

    // Q A-fragments (row = q0+lm, k = lp*8 + [0..7] (+32)); reused both passes
    const _Float16* qrow = qr + ((size_t)bh * NS + q0 + lm) * ND;
    half8 a0 = *(const half8*)(qrow + lp * 8);
    half8 a1 = *(const half8*)(qrow + 32 + lp * 8);
    const _Float16* kbase = kr + (size_t)bh * NS * ND;
    __syncthreads();

    // ---- pass 1: register row sums; wave w covers cols [w*256, w*256+256) ----
    float ps0 = 0.f, ps1 = 0.f, ps2 = 0.f, ps3 = 0.f;
    for (int kt = 0; kt < 16; ++kt) {
        int colbase = w * 256 + kt * 16;
        const _Float16* krow = kbase + (size_t)(colbase + lm) * ND;
        half8 b0 = *(const half8*)(krow + lp * 8);
        half8 b1 = *(const half8*)(krow + 32 + lp * 8);
        float4v acc = {0.f, 0.f, 0.f, 0.f};
        acc = __builtin_amdgcn_mfma_f32_16x16x32_f16(a0, b0, acc, 0, 0, 0);
        acc = __builtin_amdgcn_mfma_f32_16x16x32_f16(a1, b1, acc, 0, 0, 0);
        int word = (colbase + lm) >> 5;
        unsigned int bitm = 1u << ((colbase + lm) & 31);
        ps0 += (maskb[(lp * 4 + 0) * 64 + word] & bitm) ? __expf(acc[0] * 0.125f) : 0.f;
        ps1 += (maskb[(lp * 4 + 1) * 64 + word] & bitm) ? __expf(acc[1] * 0.125f) : 0.f;
        ps2 += (maskb[(lp * 4 + 2) * 64 + word] & bitm) ? __expf(acc[2] * 0.125f) : 0.f;
        ps3 += (maskb[(lp * 4 + 3) * 64 + word] & bitm) ? __expf(acc[3] * 0.125f) : 0.f;
    }
#pragma unroll
    for (int off = 1; off < 16; off <<= 1) {
        ps0 += __shfl_xor(ps0, off);
        ps1 += __shfl_xor(ps1, off);
        ps2 += __shfl_xor(ps2, off);
        ps3 += __shfl_xor(ps3, off);
    }
    if (lm == 0) {
        atomicAdd(&sums[lp * 4 + 0], ps0);
        atomicAdd(&sums[lp * 4 + 1], ps1);
        atomicAdd(&sums[lp * 4 + 2], ps2);
        atomicAdd(&sums[lp * 4 + 3], ps3);
    }
    __syncthreads();
    if (tid < 16) invs[tid] = (sums[tid] > 0.0f) ? (1.0f / sums[tid]) : 0.0f;
    __syncthreads();

    // ---- pass 2: chunked recompute -> score write + PV ----
    float4v oacc = {0.f, 0.f, 0.f, 0.f};
    int nt = w & 3, kh = w >> 2;          // PV ownership: d-block, k-half
    const _Float16* vbase = vt + ((size_t)bh * ND + nt * 16 + lm) * NS + kh * (CHW / 2) + lp * 8;
    float* srow = score + ((size_t)bh * NS + q0) * NS;

    for (int c = 0; c < NCH; ++c) {
        // QK^T chunk: wave w computes cols w*64 .. w*64+63 within chunk
#pragma unroll
        for (int t = 0; t < 4; ++t) {
            int lcolb   = w * 64 + t * 16;        // col within chunk
            int colbase = c * CHW + lcolb;
            const _Float16* krow = kbase + (size_t)(colbase + lm) * ND;
            half8 b0 = *(const half8*)(krow + lp * 8);
            half8 b1 = *(const half8*)(krow + 32 + lp * 8);
            float4v acc = {0.f, 0.f, 0.f, 0.f};
            acc = __builtin_amdgcn_mfma_f32_16x16x32_f16(a0, b0, acc, 0, 0, 0);
            acc = __builtin_amdgcn_mfma_f32_16x16x32_f16(a1, b1, acc, 0, 0, 0);
            int word = (colbase + lm) >> 5;
            unsigned int bitm = 1u << ((colbase + lm) & 31);
            int lcol = lcolb + lm;
#pragma unroll
            for (int r = 0; r < 4; ++r) {
                int row = lp * 4 + r;
                float ev = (maskb[row * 64 + word] & bitm) ? __expf(acc[r] * 0.125f) : 0.f;
                ebuf[row * EP + lcol] = (_Float16)ev;   // unnormalized (normal fp16 range)
            }
        }
        __syncthreads();

        // score write: 16 rows x 512 cols, normalized, 1KB-contiguous per wave
#pragma unroll
        for (int it = 0; it < 4; ++it) {
            int i  = tid + it * TPB;              // 0..2047 float4s
            int r  = i >> 7;
            int c4 = (i & 127) * 4;
            half4 hv = *(const half4*)(ebuf + r * EP + c4);
            float iv = invs[r];
            float4v f;
            f[0] = (float)hv[0] * iv;
            f[1] = (float)hv[1] * iv;
            f[2] = (float)hv[2] * iv;
            f[3] = (float)hv[3] * iv;
            *(float4v*)(srow + (size_t)r * NS + c * CHW + c4) = f;
        }

        // PV on unnormalized e: wave w does k-range [kh*256, kh*256+256) of chunk
#pragma unroll
        for (int ks = 0; ks < 8; ++ks) {
            half8 af = *(const half8*)(ebuf + lm * EP + kh * (CHW / 2) + ks * 32 + lp * 8);
            half8 bf = *(const half8*)(vbase + (size_t)c * CHW + ks * 32);
            oacc = __builtin_amdgcn_mfma_f32_16x16x32_f16(af, bf, oacc, 0, 0, 0);
        }
        __syncthreads();   // ebuf reuse for next chunk
    }

    // combine the two k-halves and write out (normalized at the end)
#pragma unroll
    for (int r = 0; r < 4; ++r)
        outb[kh * 1024 + (lp * 4 + r) * 64 + nt * 16 + lm] = oacc[r];
    __syncthreads();
    {
        float* orow = out + ((size_t)bh * NS + q0) * ND;
        for (int i = tid; i < 16 * 64; i += TPB) {
            int r = i >> 6;
            orow[i] = (outb[i] + outb[1024 + i]) * invs[r];
        }
    }
}

// ---------------------------------------------------------------------------
extern "C" void kernel_launch(void* const* d_in, const int* in_sizes, int n_in,
                              void* d_out, int out_size, void* d_ws, size_t ws_size,
                              hipStream_t stream) {
    const float* q    = (const float*)d_in[0];
    const float* k    = (const float*)d_in[1];
    const float* v    = (const float*)d_in[2];
    const int*   mask = (const int*)d_in[3];

    float* out   = (float*)d_out;            // [B,H,S,D]
    float* score = out + (size_t)NE;         // [B,H,S,S]

    _Float16* qrw = (_Float16*)d_ws;
    _Float16* krw = qrw + NE;
    _Float16* vtw = krw + NE;
    unsigned int* mp = (unsigned int*)(vtw + NE);   // NB*NS*NS/32 = 262,144 words

    static_assert(LDS_BYTES <= 160 * 1024, "LDS budget");
    (void)hipFuncSetAttribute(reinterpret_cast<const void*>(&attn_fused_kernel),
                              hipFuncAttributeMaxDynamicSharedMemorySize, LDS_BYTES);

    rope_fp16_kernel<<<dim3((NE / 2 + 255) / 256), dim3(256), 0, stream>>>(q, k, qrw, krw);
    vtrans_fp16_kernel<<<dim3((NE + 255) / 256), dim3(256), 0, stream>>>(v, vtw);
    maskpack_kernel<<<dim3(NB * NS * NS / 256), dim3(256), 0, stream>>>(mask, mp);
    attn_fused_kernel<<<dim3(NB * NH * (NS / 16)), dim3(TPB), LDS_BYTES, stream>>>(
        qrw, krw, vtw, mp, out, score);
}